// Round 6
// baseline (366.634 us; speedup 1.0000x reference)
//
#include <hip/hip_runtime.h>
#include <hip/hip_bf16.h>

#define N_NODES 50000
#define N_EDGES 400000
#define FIN     128
#define HD      512
#define SLOPE   0.2f

typedef __hip_bfloat16 bf16;
typedef __bf16 bf16x8 __attribute__((ext_vector_type(8)));
typedef __bf16 bf16x4 __attribute__((ext_vector_type(4)));
typedef float  f32x4  __attribute__((ext_vector_type(4)));

// ---------------- sentinel (workspace too small diagnostic) ----------------
__global__ void sentinel_k(float* out, int n) {
    int i = blockIdx.x * 256 + threadIdx.x;
    if (i < n) out[i] = 12288.0f;
}

// ---------------- prep: zero deg | transpose W1/Wres1 -> bf16 | wl/wr ----------------
__global__ __launch_bounds__(256) void prep_k(const float* __restrict__ W1, const float* __restrict__ Wres1,
                                              const float* __restrict__ al1, const float* __restrict__ ar1,
                                              bf16* __restrict__ W1T, bf16* __restrict__ WresT,
                                              float* __restrict__ wl, float* __restrict__ wr,
                                              int* __restrict__ deg) {
    int b = blockIdx.x;
    if (b < 196) {                       // zero deg
        int i = b * 256 + threadIdx.x;
        if (i < N_NODES) deg[i] = 0;
        return;
    }
    b -= 196;
    if (b < 512) {                       // transpose both weight matrices, 2 col-units/block
        int cu = b * 2 + (threadIdx.x >> 7);
        int k = threadIdx.x & 127;
        if (cu < 512) W1T[cu * FIN + k] = __float2bfloat16(W1[k * HD + cu]);
        else          WresT[(cu - 512) * FIN + k] = __float2bfloat16(Wres1[k * HD + (cu - 512)]);
        return;
    }
    b -= 512;                            // wl/wr: 2 blocks cover 128k x 4h
    int i = b * 256 + threadIdx.x;
    int k = i >> 2, h = i & 3;
    float sl = 0.f, sr = 0.f;
    for (int d = 0; d < 128; ++d) {
        float w = W1[k * HD + h * 128 + d];
        sl += w * al1[h * 128 + d];
        sr += w * ar1[h * 128 + d];
    }
    wl[k * 4 + h] = sl;
    wr[k * 4 + h] = sr;
}

// ---------------- el/er per node: wave-per-node ----------------
__global__ __launch_bounds__(256) void eler_k(const float* __restrict__ X,
                                              const float* __restrict__ wl, const float* __restrict__ wr,
                                              float* __restrict__ el, float* __restrict__ er) {
    int w = threadIdx.x >> 6, lane = threadIdx.x & 63;
    int n = blockIdx.x * 4 + w;
    float x1 = X[(size_t)n * FIN + lane];
    float x2 = X[(size_t)n * FIN + 64 + lane];
    float pl[4], pr[4];
#pragma unroll
    for (int h = 0; h < 4; ++h) {
        pl[h] = x1 * wl[lane * 4 + h] + x2 * wl[(lane + 64) * 4 + h];
        pr[h] = x1 * wr[lane * 4 + h] + x2 * wr[(lane + 64) * 4 + h];
    }
#pragma unroll
    for (int off = 32; off > 0; off >>= 1) {
#pragma unroll
        for (int h = 0; h < 4; ++h) {
            pl[h] += __shfl_xor(pl[h], off);
            pr[h] += __shfl_xor(pr[h], off);
        }
    }
    if (lane == 0) {
        *reinterpret_cast<float4*>(el + (size_t)n * 4) = make_float4(pl[0], pl[1], pl[2], pl[3]);
        *reinterpret_cast<float4*>(er + (size_t)n * 4) = make_float4(pr[0], pr[1], pr[2], pr[3]);
    }
}

// ---------------- CSR build ----------------
__global__ void hist_k(const int* __restrict__ dst, int* __restrict__ deg) {
    int e = blockIdx.x * 256 + threadIdx.x;
    if (e < N_EDGES) atomicAdd(&deg[dst[e]], 1);
}

// 3-phase parallel exclusive scan of deg[50000] -> rowptr/cursor
__global__ __launch_bounds__(256) void scan1_k(const int* __restrict__ deg,
                                               int* __restrict__ rowptr, int* __restrict__ blksum) {
    __shared__ int wsum[4];
    int t = threadIdx.x, b = blockIdx.x;
    int i = b * 256 + t;
    int v = (i < N_NODES) ? deg[i] : 0;
    int lane = t & 63, w = t >> 6;
    int x = v;
#pragma unroll
    for (int off = 1; off < 64; off <<= 1) {
        int y = __shfl_up(x, off);
        if (lane >= off) x += y;
    }
    if (lane == 63) wsum[w] = x;
    __syncthreads();
    int wadd = 0;
    if (w > 0) wadd += wsum[0];
    if (w > 1) wadd += wsum[1];
    if (w > 2) wadd += wsum[2];
    int incl = x + wadd;
    if (i < N_NODES) rowptr[i] = incl - v;     // block-local exclusive
    if (t == 255) blksum[b] = incl;            // block total
}

__global__ __launch_bounds__(256) void scan2_k(int* __restrict__ blksum) {
    __shared__ int wsum[4];
    int t = threadIdx.x;
    int v = (t < 196) ? blksum[t] : 0;
    int lane = t & 63, w = t >> 6;
    int x = v;
#pragma unroll
    for (int off = 1; off < 64; off <<= 1) {
        int y = __shfl_up(x, off);
        if (lane >= off) x += y;
    }
    if (lane == 63) wsum[w] = x;
    __syncthreads();
    int wadd = 0;
    if (w > 0) wadd += wsum[0];
    if (w > 1) wadd += wsum[1];
    if (w > 2) wadd += wsum[2];
    if (t < 196) blksum[t] = x + wadd - v;     // exclusive block offsets
}

__global__ __launch_bounds__(256) void scan3_k(const int* __restrict__ blksum,
                                               int* __restrict__ rowptr, int* __restrict__ cursor) {
    int b = blockIdx.x;
    int i = b * 256 + threadIdx.x;
    if (i < N_NODES) {
        int v = rowptr[i] + blksum[b];
        rowptr[i] = v;
        cursor[i] = v;
    }
    if (i == 0) rowptr[N_NODES] = N_EDGES;
}

__global__ void fill_k(const int* __restrict__ src, const int* __restrict__ dst,
                       int* __restrict__ cursor, int* __restrict__ csr) {
    int e = blockIdx.x * 256 + threadIdx.x;
    if (e < N_EDGES) {
        int pos = atomicAdd(&cursor[dst[e]], 1);
        csr[pos] = src[e];
    }
}

// ---------------- MFMA GEMM v3: loop-free wave jobs ----------------
// grid = (32 channel-tiles, 782 node-tiles), 4 waves/block.
// Wave job: 16 nodes x 16 channels for BOTH Z=X@W1 and RES=X@Wres1+b1.
// a = W fragment (stationary, L1-hot within block), b = X fragment.
// D mapping (verified R4/R5): acc[i] of lane(cl,rg) = [channel c0+rg*4+i][node m0+cl]
__global__ __launch_bounds__(256, 4) void gemm_k(const float* __restrict__ X,
                                                 const bf16* __restrict__ W1T, const bf16* __restrict__ WresT,
                                                 const float* __restrict__ bias1,
                                                 bf16* __restrict__ Z, bf16* __restrict__ RES) {
    const int w = threadIdx.x >> 6;
    const int lane = threadIdx.x & 63;
    const int cl = lane & 15;
    const int rg = lane >> 4;
    const int khi = rg * 8;
    const int c0 = blockIdx.x * 16;                 // channel tile
    const int row = blockIdx.y * 64 + w * 16 + cl;  // node
    const int rowc = row < N_NODES ? row : N_NODES - 1;
    const bool valid = row < N_NODES;

    // stationary W fragments (channel side): rows c0+cl, k = 32*ks + khi + i
    const bf16x8* wz = reinterpret_cast<const bf16x8*>(W1T + (size_t)(c0 + cl) * FIN + khi);
    const bf16x8* wr = reinterpret_cast<const bf16x8*>(WresT + (size_t)(c0 + cl) * FIN + khi);
    bf16x8 az0 = wz[0], az1 = wz[4], az2 = wz[8], az3 = wz[12];
    bf16x8 ar0 = wr[0], ar1 = wr[4], ar2 = wr[8], ar3 = wr[12];

    // X fragment (node side), f32 -> bf16 inline
    const float* xb = X + (size_t)rowc * FIN + khi;
    bf16x8 xf[4];
#pragma unroll
    for (int ks = 0; ks < 4; ++ks) {
        f32x4 u = *reinterpret_cast<const f32x4*>(xb + 32 * ks);
        f32x4 v = *reinterpret_cast<const f32x4*>(xb + 32 * ks + 4);
        bf16x8 t = {(__bf16)u[0], (__bf16)u[1], (__bf16)u[2], (__bf16)u[3],
                    (__bf16)v[0], (__bf16)v[1], (__bf16)v[2], (__bf16)v[3]};
        xf[ks] = t;
    }

    f32x4 accz = {0.f, 0.f, 0.f, 0.f};
    f32x4 accr = *reinterpret_cast<const f32x4*>(bias1 + c0 + rg * 4);
    accz = __builtin_amdgcn_mfma_f32_16x16x32_bf16(az0, xf[0], accz, 0, 0, 0);
    accz = __builtin_amdgcn_mfma_f32_16x16x32_bf16(az1, xf[1], accz, 0, 0, 0);
    accz = __builtin_amdgcn_mfma_f32_16x16x32_bf16(az2, xf[2], accz, 0, 0, 0);
    accz = __builtin_amdgcn_mfma_f32_16x16x32_bf16(az3, xf[3], accz, 0, 0, 0);
    accr = __builtin_amdgcn_mfma_f32_16x16x32_bf16(ar0, xf[0], accr, 0, 0, 0);
    accr = __builtin_amdgcn_mfma_f32_16x16x32_bf16(ar1, xf[1], accr, 0, 0, 0);
    accr = __builtin_amdgcn_mfma_f32_16x16x32_bf16(ar2, xf[2], accr, 0, 0, 0);
    accr = __builtin_amdgcn_mfma_f32_16x16x32_bf16(ar3, xf[3], accr, 0, 0, 0);

    if (valid) {
        bf16x4 vz = {(__bf16)accz[0], (__bf16)accz[1], (__bf16)accz[2], (__bf16)accz[3]};
        bf16x4 vr = {(__bf16)accr[0], (__bf16)accr[1], (__bf16)accr[2], (__bf16)accr[3]};
        *reinterpret_cast<bf16x4*>(Z + (size_t)row * HD + c0 + rg * 4) = vz;
        *reinterpret_cast<bf16x4*>(RES + (size_t)row * HD + c0 + rg * 4) = vr;
    }
}

// ---------------- layer-1 aggregation + BN + ELU + layer-2 projections ----------------
// wave-per-node; node2[n] = {z2.xyz, el2, res2.xyz, er2}
__global__ __launch_bounds__(256) void agg1_k(
    const int* __restrict__ rowptr, const int* __restrict__ csr,
    const float* __restrict__ el, const float* __restrict__ er,
    const bf16* __restrict__ Z, const bf16* __restrict__ RES,
    const float* __restrict__ bng, const float* __restrict__ bnb,
    const float* __restrict__ bnm, const float* __restrict__ bnv,
    const float* __restrict__ W2, const float* __restrict__ Wres2,
    const float* __restrict__ al2, const float* __restrict__ ar2,
    float* __restrict__ node2) {
    __shared__ int   ssrc[4][64];
    __shared__ float spe[4][64][4];

    const int w = threadIdx.x >> 6, lane = threadIdx.x & 63;
    const int n = blockIdx.x * 4 + w;
    const int beg = rowptr[n];
    const int deg = rowptr[n + 1] - beg;
    const float4 ern = *reinterpret_cast<const float4*>(er + (size_t)n * 4);
    const int head = lane >> 4;
    const int d0 = lane * 8;

    float acc[8];
#pragma unroll
    for (int i = 0; i < 8; ++i) acc[i] = 0.f;
    float4 den = make_float4(0.f, 0.f, 0.f, 0.f);

    for (int base = 0; base < deg; base += 64) {
        const int cnt = min(64, deg - base);
        if (lane < cnt) {
            int s = csr[beg + base + lane];
            ssrc[w][lane] = s;
            float4 e4 = *reinterpret_cast<const float4*>(el + (size_t)s * 4);
            float4 p;
            float e;
            e = e4.x + ern.x; e = e > 0.f ? e : SLOPE * e; p.x = __expf(e);
            e = e4.y + ern.y; e = e > 0.f ? e : SLOPE * e; p.y = __expf(e);
            e = e4.z + ern.z; e = e > 0.f ? e : SLOPE * e; p.z = __expf(e);
            e = e4.w + ern.w; e = e > 0.f ? e : SLOPE * e; p.w = __expf(e);
            den.x += p.x; den.y += p.y; den.z += p.z; den.w += p.w;
            *reinterpret_cast<float4*>(&spe[w][lane][0]) = p;
        }
        asm volatile("s_waitcnt lgkmcnt(0)" ::: "memory");
        // gather: 2-deep software pipeline
        int s_n = ssrc[w][0];
        float p_n = spe[w][0][head];
        bf16x8 zv_n = *reinterpret_cast<const bf16x8*>(Z + (size_t)s_n * HD + d0);
        for (int jj = 0; jj < cnt; ++jj) {
            bf16x8 zv = zv_n;
            float p = p_n;
            if (jj + 1 < cnt) {
                int s2 = ssrc[w][jj + 1];
                p_n = spe[w][jj + 1][head];
                zv_n = *reinterpret_cast<const bf16x8*>(Z + (size_t)s2 * HD + d0);
            }
#pragma unroll
            for (int i = 0; i < 8; ++i) acc[i] += p * (float)zv[i];
        }
        asm volatile("s_waitcnt lgkmcnt(0)" ::: "memory");   // WAR guard before next chunk
    }

    // reduce den across wave
#pragma unroll
    for (int off = 32; off > 0; off >>= 1) {
        den.x += __shfl_xor(den.x, off);
        den.y += __shfl_xor(den.y, off);
        den.z += __shfl_xor(den.z, off);
        den.w += __shfl_xor(den.w, off);
    }
    float invh = 0.f;
    if (deg > 0) {
        float i0 = 1.f / den.x, i1 = 1.f / den.y, i2 = 1.f / den.z, i3 = 1.f / den.w;
        invh = (head & 2) ? ((head & 1) ? i3 : i2) : ((head & 1) ? i1 : i0);
    }

    // epilogue: + residual(+b1 folded), BN, ELU
    bf16x8 rv = *reinterpret_cast<const bf16x8*>(RES + (size_t)n * HD + d0);
    float o[8];
    float4 m0v = *reinterpret_cast<const float4*>(bnm + d0);
    float4 m1v = *reinterpret_cast<const float4*>(bnm + d0 + 4);
    float4 v0v = *reinterpret_cast<const float4*>(bnv + d0);
    float4 v1v = *reinterpret_cast<const float4*>(bnv + d0 + 4);
    float4 g0v = *reinterpret_cast<const float4*>(bng + d0);
    float4 g1v = *reinterpret_cast<const float4*>(bng + d0 + 4);
    float4 b0v = *reinterpret_cast<const float4*>(bnb + d0);
    float4 b1v = *reinterpret_cast<const float4*>(bnb + d0 + 4);
    float bm[8] = {m0v.x, m0v.y, m0v.z, m0v.w, m1v.x, m1v.y, m1v.z, m1v.w};
    float bvv[8] = {v0v.x, v0v.y, v0v.z, v0v.w, v1v.x, v1v.y, v1v.z, v1v.w};
    float bg[8] = {g0v.x, g0v.y, g0v.z, g0v.w, g1v.x, g1v.y, g1v.z, g1v.w};
    float bb[8] = {b0v.x, b0v.y, b0v.z, b0v.w, b1v.x, b1v.y, b1v.z, b1v.w};
#pragma unroll
    for (int i = 0; i < 8; ++i) {
        float t = acc[i] * invh + (float)rv[i];
        t = (t - bm[i]) * rsqrtf(bvv[i] + 1e-5f) * bg[i] + bb[i];
        o[i] = t > 0.f ? t : (__expf(t) - 1.f);
    }

    // layer-2 projections
    float w2v[24], wrv[24];
    const f32x4* w2p = reinterpret_cast<const f32x4*>(W2 + (size_t)d0 * 3);
    const f32x4* wrp = reinterpret_cast<const f32x4*>(Wres2 + (size_t)d0 * 3);
#pragma unroll
    for (int j = 0; j < 6; ++j) {
        f32x4 a4 = w2p[j], c4 = wrp[j];
        w2v[4 * j] = a4[0]; w2v[4 * j + 1] = a4[1]; w2v[4 * j + 2] = a4[2]; w2v[4 * j + 3] = a4[3];
        wrv[4 * j] = c4[0]; wrv[4 * j + 1] = c4[1]; wrv[4 * j + 2] = c4[2]; wrv[4 * j + 3] = c4[3];
    }
    float pz[3] = {0.f, 0.f, 0.f}, pr[3] = {0.f, 0.f, 0.f};
#pragma unroll
    for (int idx = 0; idx < 24; ++idx) {
        pz[idx % 3] += o[idx / 3] * w2v[idx];
        pr[idx % 3] += o[idx / 3] * wrv[idx];
    }
#pragma unroll
    for (int off = 32; off > 0; off >>= 1) {
        pz[0] += __shfl_xor(pz[0], off); pz[1] += __shfl_xor(pz[1], off); pz[2] += __shfl_xor(pz[2], off);
        pr[0] += __shfl_xor(pr[0], off); pr[1] += __shfl_xor(pr[1], off); pr[2] += __shfl_xor(pr[2], off);
    }
    if (lane == 0) {
        float e2l = pz[0] * al2[0] + pz[1] * al2[1] + pz[2] * al2[2];
        float e2r = pz[0] * ar2[0] + pz[1] * ar2[1] + pz[2] * ar2[2];
        float4 v0 = make_float4(pz[0], pz[1], pz[2], e2l);
        float4 v1 = make_float4(pr[0], pr[1], pr[2], e2r);
        *reinterpret_cast<float4*>(node2 + (size_t)n * 8) = v0;
        *reinterpret_cast<float4*>(node2 + (size_t)n * 8 + 4) = v1;
    }
}

// ---------------- layer-2 aggregation: wave-per-node ----------------
__global__ __launch_bounds__(256) void agg2_k(const int* __restrict__ rowptr, const int* __restrict__ csr,
                                              const float* __restrict__ node2,
                                              const float* __restrict__ b2, float* __restrict__ out) {
    int wv = threadIdx.x >> 6, lane = threadIdx.x & 63;
    int n = blockIdx.x * 4 + wv;
    int beg = rowptr[n], deg = rowptr[n + 1] - beg;
    float ern = node2[(size_t)n * 8 + 7];
    float den = 0.f, a0 = 0.f, a1 = 0.f, a2 = 0.f;
    for (int j = lane; j < deg; j += 64) {
        int s = csr[beg + j];
        float4 v = *reinterpret_cast<const float4*>(node2 + (size_t)s * 8);
        float e = v.w + ern;
        e = e > 0.f ? e : SLOPE * e;
        float p = __expf(e);
        den += p;
        a0 += p * v.x; a1 += p * v.y; a2 += p * v.z;
    }
#pragma unroll
    for (int off = 32; off > 0; off >>= 1) {
        den += __shfl_xor(den, off);
        a0 += __shfl_xor(a0, off); a1 += __shfl_xor(a1, off); a2 += __shfl_xor(a2, off);
    }
    if (lane == 0) {
        float inv = deg > 0 ? 1.f / den : 0.f;
        float4 r = *reinterpret_cast<const float4*>(node2 + (size_t)n * 8 + 4);
        out[(size_t)n * 3 + 0] = a0 * inv + r.x + b2[0];
        out[(size_t)n * 3 + 1] = a1 * inv + r.y + b2[1];
        out[(size_t)n * 3 + 2] = a2 * inv + r.z + b2[2];
    }
}

extern "C" void kernel_launch(void* const* d_in, const int* in_sizes, int n_in,
                              void* d_out, int out_size, void* d_ws, size_t ws_size,
                              hipStream_t stream) {
    const float* X     = (const float*)d_in[0];
    const int*   src   = (const int*)d_in[1];
    const int*   dst   = (const int*)d_in[2];
    const float* W1    = (const float*)d_in[3];
    const float* al1   = (const float*)d_in[4];
    const float* ar1   = (const float*)d_in[5];
    const float* b1    = (const float*)d_in[6];
    const float* Wres1 = (const float*)d_in[7];
    const float* bng   = (const float*)d_in[8];
    const float* bnb   = (const float*)d_in[9];
    const float* bnm   = (const float*)d_in[10];
    const float* bnv   = (const float*)d_in[11];
    const float* W2    = (const float*)d_in[12];
    const float* al2   = (const float*)d_in[13];
    const float* ar2   = (const float*)d_in[14];
    const float* b2    = (const float*)d_in[15];
    const float* Wres2 = (const float*)d_in[16];
    float* out = (float*)d_out;

    char* p = (char*)d_ws;
    auto carve = [&](size_t bytes) -> char* {
        char* r = p;
        p += (bytes + 255) & ~(size_t)255;
        return r;
    };
    bf16*  W1T    = (bf16*)carve((size_t)HD * FIN * 2);
    bf16*  WresT  = (bf16*)carve((size_t)HD * FIN * 2);
    float* wl     = (float*)carve((size_t)FIN * 4 * 4);
    float* wr     = (float*)carve((size_t)FIN * 4 * 4);
    float* el     = (float*)carve((size_t)N_NODES * 4 * 4);
    float* er     = (float*)carve((size_t)N_NODES * 4 * 4);
    int*   deg    = (int*)carve((size_t)N_NODES * 4);
    int*   rowptr = (int*)carve((size_t)(N_NODES + 1) * 4);
    int*   cursor = (int*)carve((size_t)N_NODES * 4);
    int*   blksum = (int*)carve((size_t)256 * 4);
    int*   csr    = (int*)carve((size_t)N_EDGES * 4);
    bf16*  Z      = (bf16*)carve((size_t)N_NODES * HD * 2);
    bf16*  RES    = (bf16*)carve((size_t)N_NODES * HD * 2);
    float* node2  = (float*)carve((size_t)N_NODES * 8 * 4);
    size_t need = (size_t)(p - (char*)d_ws);
    if (need > ws_size) {
        sentinel_k<<<(out_size + 255) / 256, 256, 0, stream>>>(out, out_size);
        return;
    }

    prep_k<<<196 + 512 + 2, 256, 0, stream>>>(W1, Wres1, al1, ar1, W1T, WresT, wl, wr, deg);
    eler_k<<<N_NODES / 4, 256, 0, stream>>>(X, wl, wr, el, er);
    hist_k<<<(N_EDGES + 255) / 256, 256, 0, stream>>>(dst, deg);
    scan1_k<<<196, 256, 0, stream>>>(deg, rowptr, blksum);
    scan2_k<<<1, 256, 0, stream>>>(blksum);
    scan3_k<<<196, 256, 0, stream>>>(blksum, rowptr, cursor);
    fill_k<<<(N_EDGES + 255) / 256, 256, 0, stream>>>(src, dst, cursor, csr);
    gemm_k<<<dim3(32, (N_NODES + 63) / 64), 256, 0, stream>>>(X, W1T, WresT, b1, Z, RES);
    agg1_k<<<N_NODES / 4, 256, 0, stream>>>(rowptr, csr, el, er, Z, RES,
                                            bng, bnb, bnm, bnv, W2, Wres2, al2, ar2, node2);
    agg2_k<<<N_NODES / 4, 256, 0, stream>>>(rowptr, csr, node2, b2, out);
}

// Round 7
// 234.905 us; speedup vs baseline: 1.5608x; 1.5608x over previous
//
#include <hip/hip_runtime.h>
#include <hip/hip_bf16.h>

#define N_NODES 50000
#define N_EDGES 400000
#define FIN     128
#define HD      512
#define SLOPE   0.2f

typedef __hip_bfloat16 bf16;
typedef __bf16 bf16x8 __attribute__((ext_vector_type(8)));
typedef __bf16 bf16x4 __attribute__((ext_vector_type(4)));
typedef float  f32x4  __attribute__((ext_vector_type(4)));

// ---------------- sentinel (workspace too small diagnostic) ----------------
__global__ void sentinel_k(float* out, int n) {
    int i = blockIdx.x * 256 + threadIdx.x;
    if (i < n) out[i] = 12288.0f;
}

// ---------------- prep: zero deg | transpose W1/Wres1 -> bf16 BT[1024][128] | wl/wr ----------------
__global__ __launch_bounds__(256) void prep_k(const float* __restrict__ W1, const float* __restrict__ Wres1,
                                              const float* __restrict__ al1, const float* __restrict__ ar1,
                                              bf16* __restrict__ BT,
                                              float* __restrict__ wl, float* __restrict__ wr,
                                              int* __restrict__ deg) {
    int b = blockIdx.x;
    if (b < 196) {                       // zero deg
        int i = b * 256 + threadIdx.x;
        if (i < N_NODES) deg[i] = 0;
        return;
    }
    b -= 196;
    if (b < 512) {                       // transpose both weight matrices, 2 col-units/block
        int cu = b * 2 + (threadIdx.x >> 7);
        int k = threadIdx.x & 127;
        if (cu < 512) BT[cu * FIN + k] = __float2bfloat16(W1[k * HD + cu]);
        else          BT[cu * FIN + k] = __float2bfloat16(Wres1[k * HD + (cu - 512)]);
        return;
    }
    b -= 512;                            // wl/wr: 2 blocks cover 128k x 4h
    int i = b * 256 + threadIdx.x;
    int k = i >> 2, h = i & 3;
    float sl = 0.f, sr = 0.f;
    for (int d = 0; d < 128; ++d) {
        float w = W1[k * HD + h * 128 + d];
        sl += w * al1[h * 128 + d];
        sr += w * ar1[h * 128 + d];
    }
    wl[k * 4 + h] = sl;
    wr[k * 4 + h] = sr;
}

// ---------------- el/er per node: wave-per-node ----------------
__global__ __launch_bounds__(256) void eler_k(const float* __restrict__ X,
                                              const float* __restrict__ wl, const float* __restrict__ wr,
                                              float* __restrict__ el, float* __restrict__ er) {
    int w = threadIdx.x >> 6, lane = threadIdx.x & 63;
    int n = blockIdx.x * 4 + w;
    float x1 = X[(size_t)n * FIN + lane];
    float x2 = X[(size_t)n * FIN + 64 + lane];
    float pl[4], pr[4];
#pragma unroll
    for (int h = 0; h < 4; ++h) {
        pl[h] = x1 * wl[lane * 4 + h] + x2 * wl[(lane + 64) * 4 + h];
        pr[h] = x1 * wr[lane * 4 + h] + x2 * wr[(lane + 64) * 4 + h];
    }
#pragma unroll
    for (int off = 32; off > 0; off >>= 1) {
#pragma unroll
        for (int h = 0; h < 4; ++h) {
            pl[h] += __shfl_xor(pl[h], off);
            pr[h] += __shfl_xor(pr[h], off);
        }
    }
    if (lane == 0) {
        *reinterpret_cast<float4*>(el + (size_t)n * 4) = make_float4(pl[0], pl[1], pl[2], pl[3]);
        *reinterpret_cast<float4*>(er + (size_t)n * 4) = make_float4(pr[0], pr[1], pr[2], pr[3]);
    }
}

// ---------------- CSR build ----------------
__global__ void hist_k(const int* __restrict__ dst, int* __restrict__ deg) {
    int e = blockIdx.x * 256 + threadIdx.x;
    if (e < N_EDGES) atomicAdd(&deg[dst[e]], 1);
}

// 3-phase parallel exclusive scan of deg[50000] -> rowptr/cursor
__global__ __launch_bounds__(256) void scan1_k(const int* __restrict__ deg,
                                               int* __restrict__ rowptr, int* __restrict__ blksum) {
    __shared__ int wsum[4];
    int t = threadIdx.x, b = blockIdx.x;
    int i = b * 256 + t;
    int v = (i < N_NODES) ? deg[i] : 0;
    int lane = t & 63, w = t >> 6;
    int x = v;
#pragma unroll
    for (int off = 1; off < 64; off <<= 1) {
        int y = __shfl_up(x, off);
        if (lane >= off) x += y;
    }
    if (lane == 63) wsum[w] = x;
    __syncthreads();
    int wadd = 0;
    if (w > 0) wadd += wsum[0];
    if (w > 1) wadd += wsum[1];
    if (w > 2) wadd += wsum[2];
    int incl = x + wadd;
    if (i < N_NODES) rowptr[i] = incl - v;     // block-local exclusive
    if (t == 255) blksum[b] = incl;            // block total
}

__global__ __launch_bounds__(256) void scan2_k(int* __restrict__ blksum) {
    __shared__ int wsum[4];
    int t = threadIdx.x;
    int v = (t < 196) ? blksum[t] : 0;
    int lane = t & 63, w = t >> 6;
    int x = v;
#pragma unroll
    for (int off = 1; off < 64; off <<= 1) {
        int y = __shfl_up(x, off);
        if (lane >= off) x += y;
    }
    if (lane == 63) wsum[w] = x;
    __syncthreads();
    int wadd = 0;
    if (w > 0) wadd += wsum[0];
    if (w > 1) wadd += wsum[1];
    if (w > 2) wadd += wsum[2];
    if (t < 196) blksum[t] = x + wadd - v;     // exclusive block offsets
}

__global__ __launch_bounds__(256) void scan3_k(const int* __restrict__ blksum,
                                               int* __restrict__ rowptr, int* __restrict__ cursor) {
    int b = blockIdx.x;
    int i = b * 256 + threadIdx.x;
    if (i < N_NODES) {
        int v = rowptr[i] + blksum[b];
        rowptr[i] = v;
        cursor[i] = v;
    }
    if (i == 0) rowptr[N_NODES] = N_EDGES;
}

__global__ void fill_k(const int* __restrict__ src, const int* __restrict__ dst,
                       int* __restrict__ cursor, int* __restrict__ csr) {
    int e = blockIdx.x * 256 + threadIdx.x;
    if (e < N_EDGES) {
        int pos = atomicAdd(&cursor[dst[e]], 1);
        csr[pos] = src[e];
    }
}

// ---------------- MFMA GEMM v4: canonical LDS-staged, coalesced I/O ----------------
// ZR[50000][1024]: cols 0..511 = Z = X@W1, cols 512..1023 = RES = X@Wres1 + b1.
// Block: 64 nodes x 128 channels; K=128 single pass; 4 waves, each 64M x 32N.
// LDS XOR-swizzle: byte ^= (row&7)<<4 (256B rows).
__global__ __launch_bounds__(256) void gemm_k(const float* __restrict__ X,
                                              const bf16* __restrict__ BT,      // [1024][128] bf16
                                              const float* __restrict__ bias1,  // [512] f32
                                              bf16* __restrict__ ZR) {
    __shared__ __align__(16) bf16 XS[64 * 128];    // 16 KB (nodes)
    __shared__ __align__(16) bf16 WS[128 * 128];   // 32 KB (channels)
    char* xsb = reinterpret_cast<char*>(XS);
    char* wsb = reinterpret_cast<char*>(WS);

    const int t = threadIdx.x;
    const int w = t >> 6, lane = t & 63;
    const int cl = lane & 15, rg = lane >> 4;
    const int n0 = blockIdx.x * 128;   // channel base in [0,1024)
    const int m0 = blockIdx.y * 64;    // node base

    // stage X tile: 64 rows x 128 ch, f32 -> bf16, coalesced 16B loads
#pragma unroll
    for (int j = 0; j < 8; ++j) {
        int row = j * 8 + (t >> 5);
        int ch = (t & 31) * 4;
        int rowc = m0 + row; rowc = rowc < N_NODES ? rowc : N_NODES - 1;
        f32x4 v = *reinterpret_cast<const f32x4*>(X + (size_t)rowc * FIN + ch);
        bf16x4 bv = {(__bf16)v[0], (__bf16)v[1], (__bf16)v[2], (__bf16)v[3]};
        int byte = (row * 256 + ch * 2) ^ ((row & 7) << 4);
        *reinterpret_cast<bf16x4*>(xsb + byte) = bv;
    }
    // stage W tile: 128 rows x 128 k, bf16, coalesced 16B loads
#pragma unroll
    for (int j = 0; j < 8; ++j) {
        int L = j * 4096 + t * 16;
        int row = L >> 8;
        bf16x8 v = *reinterpret_cast<const bf16x8*>(reinterpret_cast<const char*>(BT) + (size_t)n0 * 256 + L);
        int byte = L ^ ((row & 7) << 4);
        *reinterpret_cast<bf16x8*>(wsb + byte) = v;
    }
    __syncthreads();

    // W fragments: wave w owns channels [w*32, w*32+32)
    bf16x8 wf[2][4];
#pragma unroll
    for (int ct = 0; ct < 2; ++ct) {
        int rowW = w * 32 + ct * 16 + cl;
#pragma unroll
        for (int ks = 0; ks < 4; ++ks) {
            int byte = (rowW * 256 + ks * 64 + rg * 16) ^ ((rowW & 7) << 4);
            wf[ct][ks] = *reinterpret_cast<const bf16x8*>(wsb + byte);
        }
    }
    // bias init (RES half only)
    f32x4 binit[2];
#pragma unroll
    for (int ct = 0; ct < 2; ++ct) {
        f32x4 z = {0.f, 0.f, 0.f, 0.f};
        if (n0 >= 512) z = *reinterpret_cast<const f32x4*>(bias1 + (n0 - 512) + w * 32 + ct * 16 + rg * 4);
        binit[ct] = z;
    }

    f32x4 acc[4][2];
#pragma unroll
    for (int mt = 0; mt < 4; ++mt) {
        int rowX = mt * 16 + cl;
        bf16x8 xf[4];
#pragma unroll
        for (int ks = 0; ks < 4; ++ks) {
            int byte = (rowX * 256 + ks * 64 + rg * 16) ^ ((rowX & 7) << 4);
            xf[ks] = *reinterpret_cast<const bf16x8*>(xsb + byte);
        }
#pragma unroll
        for (int ct = 0; ct < 2; ++ct) {
            f32x4 a = binit[ct];
            a = __builtin_amdgcn_mfma_f32_16x16x32_bf16(wf[ct][0], xf[0], a, 0, 0, 0);
            a = __builtin_amdgcn_mfma_f32_16x16x32_bf16(wf[ct][1], xf[1], a, 0, 0, 0);
            a = __builtin_amdgcn_mfma_f32_16x16x32_bf16(wf[ct][2], xf[2], a, 0, 0, 0);
            a = __builtin_amdgcn_mfma_f32_16x16x32_bf16(wf[ct][3], xf[3], a, 0, 0, 0);
            acc[mt][ct] = a;
        }
    }
    __syncthreads();   // done reading XS -> reuse as output staging

    // epilogue: acc -> LDS (bf16), D-map: channel = rg*4+i, node = cl
#pragma unroll
    for (int mt = 0; mt < 4; ++mt) {
#pragma unroll
        for (int ct = 0; ct < 2; ++ct) {
            int row = mt * 16 + cl;
            int chb = (w * 32 + ct * 16 + rg * 4) * 2;   // byte offset within 256B row
            bf16x4 bv = {(__bf16)acc[mt][ct][0], (__bf16)acc[mt][ct][1],
                         (__bf16)acc[mt][ct][2], (__bf16)acc[mt][ct][3]};
            int byte = (row * 256 + chb) ^ ((row & 7) << 4);
            *reinterpret_cast<bf16x4*>(xsb + byte) = bv;
        }
    }
    __syncthreads();

    // coalesced store: 16 rows x 256B contiguous per iteration
#pragma unroll
    for (int j = 0; j < 4; ++j) {
        int row = j * 16 + (t >> 4);
        int c = (t & 15) * 16;
        int byte = (row * 256 + c) ^ ((row & 7) << 4);
        bf16x8 v = *reinterpret_cast<const bf16x8*>(xsb + byte);
        int grow = m0 + row;
        if (grow < N_NODES)
            *reinterpret_cast<bf16x8*>(reinterpret_cast<char*>(ZR) + (size_t)grow * 2048 + n0 * 2 + c) = v;
    }
}

// ---------------- layer-1 aggregation + BN + ELU + layer-2 projections ----------------
// wave-per-node; node2[n] = {z2.xyz, el2, res2.xyz, er2}
__global__ __launch_bounds__(256) void agg1_k(
    const int* __restrict__ rowptr, const int* __restrict__ csr,
    const float* __restrict__ el, const float* __restrict__ er,
    const bf16* __restrict__ ZR,
    const float* __restrict__ bng, const float* __restrict__ bnb,
    const float* __restrict__ bnm, const float* __restrict__ bnv,
    const float* __restrict__ W2, const float* __restrict__ Wres2,
    const float* __restrict__ al2, const float* __restrict__ ar2,
    float* __restrict__ node2) {
    __shared__ int   ssrc[4][64];
    __shared__ float spe[4][64][4];

    const int w = threadIdx.x >> 6, lane = threadIdx.x & 63;
    const int n = blockIdx.x * 4 + w;
    const int beg = rowptr[n];
    const int deg = rowptr[n + 1] - beg;
    const float4 ern = *reinterpret_cast<const float4*>(er + (size_t)n * 4);
    const int head = lane >> 4;
    const int d0 = lane * 8;

    float acc[8];
#pragma unroll
    for (int i = 0; i < 8; ++i) acc[i] = 0.f;
    float4 den = make_float4(0.f, 0.f, 0.f, 0.f);

    for (int base = 0; base < deg; base += 64) {
        const int cnt = min(64, deg - base);
        if (lane < cnt) {
            int s = csr[beg + base + lane];
            ssrc[w][lane] = s;
            float4 e4 = *reinterpret_cast<const float4*>(el + (size_t)s * 4);
            float4 p;
            float e;
            e = e4.x + ern.x; e = e > 0.f ? e : SLOPE * e; p.x = __expf(e);
            e = e4.y + ern.y; e = e > 0.f ? e : SLOPE * e; p.y = __expf(e);
            e = e4.z + ern.z; e = e > 0.f ? e : SLOPE * e; p.z = __expf(e);
            e = e4.w + ern.w; e = e > 0.f ? e : SLOPE * e; p.w = __expf(e);
            den.x += p.x; den.y += p.y; den.z += p.z; den.w += p.w;
            *reinterpret_cast<float4*>(&spe[w][lane][0]) = p;
        }
        asm volatile("s_waitcnt lgkmcnt(0)" ::: "memory");
        // gather: 2-deep software pipeline
        int s_n = ssrc[w][0];
        float p_n = spe[w][0][head];
        bf16x8 zv_n = *reinterpret_cast<const bf16x8*>(ZR + (size_t)s_n * 1024 + d0);
        for (int jj = 0; jj < cnt; ++jj) {
            bf16x8 zv = zv_n;
            float p = p_n;
            if (jj + 1 < cnt) {
                int s2 = ssrc[w][jj + 1];
                p_n = spe[w][jj + 1][head];
                zv_n = *reinterpret_cast<const bf16x8*>(ZR + (size_t)s2 * 1024 + d0);
            }
#pragma unroll
            for (int i = 0; i < 8; ++i) acc[i] += p * (float)zv[i];
        }
        asm volatile("s_waitcnt lgkmcnt(0)" ::: "memory");   // WAR guard before next chunk
    }

    // reduce den across wave
#pragma unroll
    for (int off = 32; off > 0; off >>= 1) {
        den.x += __shfl_xor(den.x, off);
        den.y += __shfl_xor(den.y, off);
        den.z += __shfl_xor(den.z, off);
        den.w += __shfl_xor(den.w, off);
    }
    float invh = 0.f;
    if (deg > 0) {
        float i0 = 1.f / den.x, i1 = 1.f / den.y, i2 = 1.f / den.z, i3 = 1.f / den.w;
        invh = (head & 2) ? ((head & 1) ? i3 : i2) : ((head & 1) ? i1 : i0);
    }

    // epilogue: + residual(+b1 folded), BN, ELU
    bf16x8 rv = *reinterpret_cast<const bf16x8*>(ZR + (size_t)n * 1024 + 512 + d0);
    float o[8];
    float4 m0v = *reinterpret_cast<const float4*>(bnm + d0);
    float4 m1v = *reinterpret_cast<const float4*>(bnm + d0 + 4);
    float4 v0v = *reinterpret_cast<const float4*>(bnv + d0);
    float4 v1v = *reinterpret_cast<const float4*>(bnv + d0 + 4);
    float4 g0v = *reinterpret_cast<const float4*>(bng + d0);
    float4 g1v = *reinterpret_cast<const float4*>(bng + d0 + 4);
    float4 b0v = *reinterpret_cast<const float4*>(bnb + d0);
    float4 b1v = *reinterpret_cast<const float4*>(bnb + d0 + 4);
    float bm[8] = {m0v.x, m0v.y, m0v.z, m0v.w, m1v.x, m1v.y, m1v.z, m1v.w};
    float bvv[8] = {v0v.x, v0v.y, v0v.z, v0v.w, v1v.x, v1v.y, v1v.z, v1v.w};
    float bg[8] = {g0v.x, g0v.y, g0v.z, g0v.w, g1v.x, g1v.y, g1v.z, g1v.w};
    float bb[8] = {b0v.x, b0v.y, b0v.z, b0v.w, b1v.x, b1v.y, b1v.z, b1v.w};
#pragma unroll
    for (int i = 0; i < 8; ++i) {
        float tt = acc[i] * invh + (float)rv[i];
        tt = (tt - bm[i]) * rsqrtf(bvv[i] + 1e-5f) * bg[i] + bb[i];
        o[i] = tt > 0.f ? tt : (__expf(tt) - 1.f);
    }

    // layer-2 projections
    float w2v[24], wrv[24];
    const f32x4* w2p = reinterpret_cast<const f32x4*>(W2 + (size_t)d0 * 3);
    const f32x4* wrp = reinterpret_cast<const f32x4*>(Wres2 + (size_t)d0 * 3);
#pragma unroll
    for (int j = 0; j < 6; ++j) {
        f32x4 a4 = w2p[j], c4 = wrp[j];
        w2v[4 * j] = a4[0]; w2v[4 * j + 1] = a4[1]; w2v[4 * j + 2] = a4[2]; w2v[4 * j + 3] = a4[3];
        wrv[4 * j] = c4[0]; wrv[4 * j + 1] = c4[1]; wrv[4 * j + 2] = c4[2]; wrv[4 * j + 3] = c4[3];
    }
    float pz[3] = {0.f, 0.f, 0.f}, pr[3] = {0.f, 0.f, 0.f};
#pragma unroll
    for (int idx = 0; idx < 24; ++idx) {
        pz[idx % 3] += o[idx / 3] * w2v[idx];
        pr[idx % 3] += o[idx / 3] * wrv[idx];
    }
#pragma unroll
    for (int off = 32; off > 0; off >>= 1) {
        pz[0] += __shfl_xor(pz[0], off); pz[1] += __shfl_xor(pz[1], off); pz[2] += __shfl_xor(pz[2], off);
        pr[0] += __shfl_xor(pr[0], off); pr[1] += __shfl_xor(pr[1], off); pr[2] += __shfl_xor(pr[2], off);
    }
    if (lane == 0) {
        float e2l = pz[0] * al2[0] + pz[1] * al2[1] + pz[2] * al2[2];
        float e2r = pz[0] * ar2[0] + pz[1] * ar2[1] + pz[2] * ar2[2];
        float4 v0 = make_float4(pz[0], pz[1], pz[2], e2l);
        float4 v1 = make_float4(pr[0], pr[1], pr[2], e2r);
        *reinterpret_cast<float4*>(node2 + (size_t)n * 8) = v0;
        *reinterpret_cast<float4*>(node2 + (size_t)n * 8 + 4) = v1;
    }
}

// ---------------- layer-2 aggregation: wave-per-node ----------------
__global__ __launch_bounds__(256) void agg2_k(const int* __restrict__ rowptr, const int* __restrict__ csr,
                                              const float* __restrict__ node2,
                                              const float* __restrict__ b2, float* __restrict__ out) {
    int wv = threadIdx.x >> 6, lane = threadIdx.x & 63;
    int n = blockIdx.x * 4 + wv;
    int beg = rowptr[n], deg = rowptr[n + 1] - beg;
    float ern = node2[(size_t)n * 8 + 7];
    float den = 0.f, a0 = 0.f, a1 = 0.f, a2 = 0.f;
    for (int j = lane; j < deg; j += 64) {
        int s = csr[beg + j];
        float4 v = *reinterpret_cast<const float4*>(node2 + (size_t)s * 8);
        float e = v.w + ern;
        e = e > 0.f ? e : SLOPE * e;
        float p = __expf(e);
        den += p;
        a0 += p * v.x; a1 += p * v.y; a2 += p * v.z;
    }
#pragma unroll
    for (int off = 32; off > 0; off >>= 1) {
        den += __shfl_xor(den, off);
        a0 += __shfl_xor(a0, off); a1 += __shfl_xor(a1, off); a2 += __shfl_xor(a2, off);
    }
    if (lane == 0) {
        float inv = deg > 0 ? 1.f / den : 0.f;
        float4 r = *reinterpret_cast<const float4*>(node2 + (size_t)n * 8 + 4);
        out[(size_t)n * 3 + 0] = a0 * inv + r.x + b2[0];
        out[(size_t)n * 3 + 1] = a1 * inv + r.y + b2[1];
        out[(size_t)n * 3 + 2] = a2 * inv + r.z + b2[2];
    }
}

extern "C" void kernel_launch(void* const* d_in, const int* in_sizes, int n_in,
                              void* d_out, int out_size, void* d_ws, size_t ws_size,
                              hipStream_t stream) {
    const float* X     = (const float*)d_in[0];
    const int*   src   = (const int*)d_in[1];
    const int*   dst   = (const int*)d_in[2];
    const float* W1    = (const float*)d_in[3];
    const float* al1   = (const float*)d_in[4];
    const float* ar1   = (const float*)d_in[5];
    const float* b1    = (const float*)d_in[6];
    const float* Wres1 = (const float*)d_in[7];
    const float* bng   = (const float*)d_in[8];
    const float* bnb   = (const float*)d_in[9];
    const float* bnm   = (const float*)d_in[10];
    const float* bnv   = (const float*)d_in[11];
    const float* W2    = (const float*)d_in[12];
    const float* al2   = (const float*)d_in[13];
    const float* ar2   = (const float*)d_in[14];
    const float* b2    = (const float*)d_in[15];
    const float* Wres2 = (const float*)d_in[16];
    float* out = (float*)d_out;

    char* p = (char*)d_ws;
    auto carve = [&](size_t bytes) -> char* {
        char* r = p;
        p += (bytes + 255) & ~(size_t)255;
        return r;
    };
    bf16*  BT     = (bf16*)carve((size_t)1024 * FIN * 2);   // [1024][128]: W1T rows 0-511, WresT rows 512-1023
    float* wl     = (float*)carve((size_t)FIN * 4 * 4);
    float* wr     = (float*)carve((size_t)FIN * 4 * 4);
    float* el     = (float*)carve((size_t)N_NODES * 4 * 4);
    float* er     = (float*)carve((size_t)N_NODES * 4 * 4);
    int*   deg    = (int*)carve((size_t)N_NODES * 4);
    int*   rowptr = (int*)carve((size_t)(N_NODES + 1) * 4);
    int*   cursor = (int*)carve((size_t)N_NODES * 4);
    int*   blksum = (int*)carve((size_t)256 * 4);
    int*   csr    = (int*)carve((size_t)N_EDGES * 4);
    bf16*  ZR     = (bf16*)carve((size_t)N_NODES * 1024 * 2);
    float* node2  = (float*)carve((size_t)N_NODES * 8 * 4);
    size_t need = (size_t)(p - (char*)d_ws);
    if (need > ws_size) {
        sentinel_k<<<(out_size + 255) / 256, 256, 0, stream>>>(out, out_size);
        return;
    }

    prep_k<<<196 + 512 + 2, 256, 0, stream>>>(W1, Wres1, al1, ar1, BT, wl, wr, deg);
    eler_k<<<N_NODES / 4, 256, 0, stream>>>(X, wl, wr, el, er);
    hist_k<<<(N_EDGES + 255) / 256, 256, 0, stream>>>(dst, deg);
    scan1_k<<<196, 256, 0, stream>>>(deg, rowptr, blksum);
    scan2_k<<<1, 256, 0, stream>>>(blksum);
    scan3_k<<<196, 256, 0, stream>>>(blksum, rowptr, cursor);
    fill_k<<<(N_EDGES + 255) / 256, 256, 0, stream>>>(src, dst, cursor, csr);
    gemm_k<<<dim3(8, (N_NODES + 63) / 64), 256, 0, stream>>>(X, BT, b1, ZR);
    agg1_k<<<N_NODES / 4, 256, 0, stream>>>(rowptr, csr, el, er, ZR,
                                            bng, bnb, bnm, bnv, W2, Wres2, al2, ar2, node2);
    agg2_k<<<N_NODES / 4, 256, 0, stream>>>(rowptr, csr, node2, b2, out);
}

// Round 8
// 228.484 us; speedup vs baseline: 1.6046x; 1.0281x over previous
//
#include <hip/hip_runtime.h>
#include <hip/hip_bf16.h>

#define N_NODES 50000
#define N_EDGES 400000
#define FIN     128
#define HD      512
#define SLOPE   0.2f

typedef __hip_bfloat16 bf16;
typedef __bf16 bf16x8 __attribute__((ext_vector_type(8)));
typedef __bf16 bf16x4 __attribute__((ext_vector_type(4)));
typedef float  f32x4  __attribute__((ext_vector_type(4)));

// ---------------- sentinel (workspace too small diagnostic) ----------------
__global__ void sentinel_k(float* out, int n) {
    int i = blockIdx.x * 256 + threadIdx.x;
    if (i < n) out[i] = 12288.0f;
}

// ---------------- prep: zero deg | transpose W1/Wres1 -> bf16 BT[1024][128] | wl/wr ----------------
__global__ __launch_bounds__(256) void prep_k(const float* __restrict__ W1, const float* __restrict__ Wres1,
                                              const float* __restrict__ al1, const float* __restrict__ ar1,
                                              bf16* __restrict__ BT,
                                              float* __restrict__ wl, float* __restrict__ wr,
                                              int* __restrict__ deg) {
    int b = blockIdx.x;
    if (b < 196) {                       // zero deg
        int i = b * 256 + threadIdx.x;
        if (i < N_NODES) deg[i] = 0;
        return;
    }
    b -= 196;
    if (b < 512) {                       // transpose both weight matrices, 2 col-units/block
        int cu = b * 2 + (threadIdx.x >> 7);
        int k = threadIdx.x & 127;
        if (cu < 512) BT[cu * FIN + k] = __float2bfloat16(W1[k * HD + cu]);
        else          BT[cu * FIN + k] = __float2bfloat16(Wres1[k * HD + (cu - 512)]);
        return;
    }
    b -= 512;                            // wl/wr: 2 blocks cover 128k x 4h
    int i = b * 256 + threadIdx.x;
    int k = i >> 2, h = i & 3;
    float sl = 0.f, sr = 0.f;
    for (int d = 0; d < 128; ++d) {
        float w = W1[k * HD + h * 128 + d];
        sl += w * al1[h * 128 + d];
        sr += w * ar1[h * 128 + d];
    }
    wl[k * 4 + h] = sl;
    wr[k * 4 + h] = sr;
}

// ---------------- el/er per node: wave-per-node ----------------
__global__ __launch_bounds__(256) void eler_k(const float* __restrict__ X,
                                              const float* __restrict__ wl, const float* __restrict__ wr,
                                              float* __restrict__ el, float* __restrict__ er) {
    int w = threadIdx.x >> 6, lane = threadIdx.x & 63;
    int n = blockIdx.x * 4 + w;
    float x1 = X[(size_t)n * FIN + lane];
    float x2 = X[(size_t)n * FIN + 64 + lane];
    float pl[4], pr[4];
#pragma unroll
    for (int h = 0; h < 4; ++h) {
        pl[h] = x1 * wl[lane * 4 + h] + x2 * wl[(lane + 64) * 4 + h];
        pr[h] = x1 * wr[lane * 4 + h] + x2 * wr[(lane + 64) * 4 + h];
    }
#pragma unroll
    for (int off = 32; off > 0; off >>= 1) {
#pragma unroll
        for (int h = 0; h < 4; ++h) {
            pl[h] += __shfl_xor(pl[h], off);
            pr[h] += __shfl_xor(pr[h], off);
        }
    }
    if (lane == 0) {
        *reinterpret_cast<float4*>(el + (size_t)n * 4) = make_float4(pl[0], pl[1], pl[2], pl[3]);
        *reinterpret_cast<float4*>(er + (size_t)n * 4) = make_float4(pr[0], pr[1], pr[2], pr[3]);
    }
}

// ---------------- CSR build ----------------
__global__ void hist_k(const int* __restrict__ dst, int* __restrict__ deg) {
    int e = blockIdx.x * 256 + threadIdx.x;
    if (e < N_EDGES) atomicAdd(&deg[dst[e]], 1);
}

// 3-phase parallel exclusive scan of deg[50000] -> rowptr/cursor
__global__ __launch_bounds__(256) void scan1_k(const int* __restrict__ deg,
                                               int* __restrict__ rowptr, int* __restrict__ blksum) {
    __shared__ int wsum[4];
    int t = threadIdx.x, b = blockIdx.x;
    int i = b * 256 + t;
    int v = (i < N_NODES) ? deg[i] : 0;
    int lane = t & 63, w = t >> 6;
    int x = v;
#pragma unroll
    for (int off = 1; off < 64; off <<= 1) {
        int y = __shfl_up(x, off);
        if (lane >= off) x += y;
    }
    if (lane == 63) wsum[w] = x;
    __syncthreads();
    int wadd = 0;
    if (w > 0) wadd += wsum[0];
    if (w > 1) wadd += wsum[1];
    if (w > 2) wadd += wsum[2];
    int incl = x + wadd;
    if (i < N_NODES) rowptr[i] = incl - v;     // block-local exclusive
    if (t == 255) blksum[b] = incl;            // block total
}

__global__ __launch_bounds__(256) void scan2_k(int* __restrict__ blksum) {
    __shared__ int wsum[4];
    int t = threadIdx.x;
    int v = (t < 196) ? blksum[t] : 0;
    int lane = t & 63, w = t >> 6;
    int x = v;
#pragma unroll
    for (int off = 1; off < 64; off <<= 1) {
        int y = __shfl_up(x, off);
        if (lane >= off) x += y;
    }
    if (lane == 63) wsum[w] = x;
    __syncthreads();
    int wadd = 0;
    if (w > 0) wadd += wsum[0];
    if (w > 1) wadd += wsum[1];
    if (w > 2) wadd += wsum[2];
    if (t < 196) blksum[t] = x + wadd - v;     // exclusive block offsets
}

__global__ __launch_bounds__(256) void scan3_k(const int* __restrict__ blksum,
                                               int* __restrict__ rowptr, int* __restrict__ cursor) {
    int b = blockIdx.x;
    int i = b * 256 + threadIdx.x;
    if (i < N_NODES) {
        int v = rowptr[i] + blksum[b];
        rowptr[i] = v;
        cursor[i] = v;
    }
    if (i == 0) rowptr[N_NODES] = N_EDGES;
}

__global__ void fill_k(const int* __restrict__ src, const int* __restrict__ dst,
                       int* __restrict__ cursor, int* __restrict__ csr) {
    int e = blockIdx.x * 256 + threadIdx.x;
    if (e < N_EDGES) {
        int pos = atomicAdd(&cursor[dst[e]], 1);
        csr[pos] = src[e];
    }
}

// ---------------- MFMA GEMM v4: canonical LDS-staged, coalesced I/O ----------------
// ZR[50000][1024]: cols 0..511 = Z = X@W1, cols 512..1023 = RES = X@Wres1 + b1.
// Block: 64 nodes x 128 channels; K=128 single pass; 4 waves, each 64M x 32N.
// LDS XOR-swizzle: byte ^= (row&7)<<4 (256B rows).
__global__ __launch_bounds__(256) void gemm_k(const float* __restrict__ X,
                                              const bf16* __restrict__ BT,      // [1024][128] bf16
                                              const float* __restrict__ bias1,  // [512] f32
                                              bf16* __restrict__ ZR) {
    __shared__ __align__(16) bf16 XS[64 * 128];    // 16 KB (nodes)
    __shared__ __align__(16) bf16 WS[128 * 128];   // 32 KB (channels)
    char* xsb = reinterpret_cast<char*>(XS);
    char* wsb = reinterpret_cast<char*>(WS);

    const int t = threadIdx.x;
    const int w = t >> 6, lane = t & 63;
    const int cl = lane & 15, rg = lane >> 4;
    const int n0 = blockIdx.x * 128;   // channel base in [0,1024)
    const int m0 = blockIdx.y * 64;    // node base

    // stage X tile: 64 rows x 128 ch, f32 -> bf16, coalesced 16B loads
#pragma unroll
    for (int j = 0; j < 8; ++j) {
        int row = j * 8 + (t >> 5);
        int ch = (t & 31) * 4;
        int rowc = m0 + row; rowc = rowc < N_NODES ? rowc : N_NODES - 1;
        f32x4 v = *reinterpret_cast<const f32x4*>(X + (size_t)rowc * FIN + ch);
        bf16x4 bv = {(__bf16)v[0], (__bf16)v[1], (__bf16)v[2], (__bf16)v[3]};
        int byte = (row * 256 + ch * 2) ^ ((row & 7) << 4);
        *reinterpret_cast<bf16x4*>(xsb + byte) = bv;
    }
    // stage W tile: 128 rows x 128 k, bf16, coalesced 16B loads
#pragma unroll
    for (int j = 0; j < 8; ++j) {
        int L = j * 4096 + t * 16;
        int row = L >> 8;
        bf16x8 v = *reinterpret_cast<const bf16x8*>(reinterpret_cast<const char*>(BT) + (size_t)n0 * 256 + L);
        int byte = L ^ ((row & 7) << 4);
        *reinterpret_cast<bf16x8*>(wsb + byte) = v;
    }
    __syncthreads();

    // W fragments: wave w owns channels [w*32, w*32+32)
    bf16x8 wf[2][4];
#pragma unroll
    for (int ct = 0; ct < 2; ++ct) {
        int rowW = w * 32 + ct * 16 + cl;
#pragma unroll
        for (int ks = 0; ks < 4; ++ks) {
            int byte = (rowW * 256 + ks * 64 + rg * 16) ^ ((rowW & 7) << 4);
            wf[ct][ks] = *reinterpret_cast<const bf16x8*>(wsb + byte);
        }
    }
    // bias init (RES half only)
    f32x4 binit[2];
#pragma unroll
    for (int ct = 0; ct < 2; ++ct) {
        f32x4 z = {0.f, 0.f, 0.f, 0.f};
        if (n0 >= 512) z = *reinterpret_cast<const f32x4*>(bias1 + (n0 - 512) + w * 32 + ct * 16 + rg * 4);
        binit[ct] = z;
    }

    f32x4 acc[4][2];
#pragma unroll
    for (int mt = 0; mt < 4; ++mt) {
        int rowX = mt * 16 + cl;
        bf16x8 xf[4];
#pragma unroll
        for (int ks = 0; ks < 4; ++ks) {
            int byte = (rowX * 256 + ks * 64 + rg * 16) ^ ((rowX & 7) << 4);
            xf[ks] = *reinterpret_cast<const bf16x8*>(xsb + byte);
        }
#pragma unroll
        for (int ct = 0; ct < 2; ++ct) {
            f32x4 a = binit[ct];
            a = __builtin_amdgcn_mfma_f32_16x16x32_bf16(wf[ct][0], xf[0], a, 0, 0, 0);
            a = __builtin_amdgcn_mfma_f32_16x16x32_bf16(wf[ct][1], xf[1], a, 0, 0, 0);
            a = __builtin_amdgcn_mfma_f32_16x16x32_bf16(wf[ct][2], xf[2], a, 0, 0, 0);
            a = __builtin_amdgcn_mfma_f32_16x16x32_bf16(wf[ct][3], xf[3], a, 0, 0, 0);
            acc[mt][ct] = a;
        }
    }
    __syncthreads();   // done reading XS -> reuse as output staging

    // epilogue: acc -> LDS (bf16), D-map: channel = rg*4+i, node = cl
#pragma unroll
    for (int mt = 0; mt < 4; ++mt) {
#pragma unroll
        for (int ct = 0; ct < 2; ++ct) {
            int row = mt * 16 + cl;
            int chb = (w * 32 + ct * 16 + rg * 4) * 2;   // byte offset within 256B row
            bf16x4 bv = {(__bf16)acc[mt][ct][0], (__bf16)acc[mt][ct][1],
                         (__bf16)acc[mt][ct][2], (__bf16)acc[mt][ct][3]};
            int byte = (row * 256 + chb) ^ ((row & 7) << 4);
            *reinterpret_cast<bf16x4*>(xsb + byte) = bv;
        }
    }
    __syncthreads();

    // coalesced store: 16 rows x 256B contiguous per iteration
#pragma unroll
    for (int j = 0; j < 4; ++j) {
        int row = j * 16 + (t >> 4);
        int c = (t & 15) * 16;
        int byte = (row * 256 + c) ^ ((row & 7) << 4);
        bf16x8 v = *reinterpret_cast<const bf16x8*>(xsb + byte);
        int grow = m0 + row;
        if (grow < N_NODES)
            *reinterpret_cast<bf16x8*>(reinterpret_cast<char*>(ZR) + (size_t)grow * 2048 + n0 * 2 + c) = v;
    }
}

// ---------------- layer-1 aggregation + BN + ELU + layer-2 projections ----------------
// wave-per-node; node2[n] = {z2.xyz, el2, res2.xyz, er2}
// gather loop batched 4-wide: 4 outstanding b128 loads per lane (MLP)
__global__ __launch_bounds__(256) void agg1_k(
    const int* __restrict__ rowptr, const int* __restrict__ csr,
    const float* __restrict__ el, const float* __restrict__ er,
    const bf16* __restrict__ ZR,
    const float* __restrict__ bng, const float* __restrict__ bnb,
    const float* __restrict__ bnm, const float* __restrict__ bnv,
    const float* __restrict__ W2, const float* __restrict__ Wres2,
    const float* __restrict__ al2, const float* __restrict__ ar2,
    float* __restrict__ node2) {
    __shared__ int   ssrc[4][64];
    __shared__ float spe[4][64][4];

    const int w = threadIdx.x >> 6, lane = threadIdx.x & 63;
    const int n = blockIdx.x * 4 + w;
    const int beg = rowptr[n];
    const int deg = rowptr[n + 1] - beg;
    const float4 ern = *reinterpret_cast<const float4*>(er + (size_t)n * 4);
    const int head = lane >> 4;
    const int d0 = lane * 8;

    float acc[8];
#pragma unroll
    for (int i = 0; i < 8; ++i) acc[i] = 0.f;
    float4 den = make_float4(0.f, 0.f, 0.f, 0.f);

    for (int base = 0; base < deg; base += 64) {
        const int cnt = min(64, deg - base);
        if (lane < cnt) {
            int s = csr[beg + base + lane];
            ssrc[w][lane] = s;
            float4 e4 = *reinterpret_cast<const float4*>(el + (size_t)s * 4);
            float4 p;
            float e;
            e = e4.x + ern.x; e = e > 0.f ? e : SLOPE * e; p.x = __expf(e);
            e = e4.y + ern.y; e = e > 0.f ? e : SLOPE * e; p.y = __expf(e);
            e = e4.z + ern.z; e = e > 0.f ? e : SLOPE * e; p.z = __expf(e);
            e = e4.w + ern.w; e = e > 0.f ? e : SLOPE * e; p.w = __expf(e);
            den.x += p.x; den.y += p.y; den.z += p.z; den.w += p.w;
            *reinterpret_cast<float4*>(&spe[w][lane][0]) = p;
        }
        asm volatile("s_waitcnt lgkmcnt(0)" ::: "memory");
        // gather: 4-wide batch, clamped tail (p=0 for OOB -> correct, no fault)
        for (int jj = 0; jj < cnt; jj += 4) {
            float p4[4];
            bf16x8 zv4[4];
#pragma unroll
            for (int k = 0; k < 4; ++k) {
                int j2 = jj + k;
                int jc = j2 < cnt ? j2 : cnt - 1;
                int s = ssrc[w][jc];
                zv4[k] = *reinterpret_cast<const bf16x8*>(ZR + (size_t)s * 1024 + d0);
                p4[k] = j2 < cnt ? spe[w][jc][head] : 0.f;
            }
#pragma unroll
            for (int k = 0; k < 4; ++k) {
#pragma unroll
                for (int i = 0; i < 8; ++i) acc[i] += p4[k] * (float)zv4[k][i];
            }
        }
        asm volatile("s_waitcnt lgkmcnt(0)" ::: "memory");   // WAR guard before next chunk
    }

    // reduce den across wave
#pragma unroll
    for (int off = 32; off > 0; off >>= 1) {
        den.x += __shfl_xor(den.x, off);
        den.y += __shfl_xor(den.y, off);
        den.z += __shfl_xor(den.z, off);
        den.w += __shfl_xor(den.w, off);
    }
    float invh = 0.f;
    if (deg > 0) {
        float i0 = 1.f / den.x, i1 = 1.f / den.y, i2 = 1.f / den.z, i3 = 1.f / den.w;
        invh = (head & 2) ? ((head & 1) ? i3 : i2) : ((head & 1) ? i1 : i0);
    }

    // epilogue: + residual(+b1 folded), BN, ELU
    bf16x8 rv = *reinterpret_cast<const bf16x8*>(ZR + (size_t)n * 1024 + 512 + d0);
    float o[8];
    float4 m0v = *reinterpret_cast<const float4*>(bnm + d0);
    float4 m1v = *reinterpret_cast<const float4*>(bnm + d0 + 4);
    float4 v0v = *reinterpret_cast<const float4*>(bnv + d0);
    float4 v1v = *reinterpret_cast<const float4*>(bnv + d0 + 4);
    float4 g0v = *reinterpret_cast<const float4*>(bng + d0);
    float4 g1v = *reinterpret_cast<const float4*>(bng + d0 + 4);
    float4 b0v = *reinterpret_cast<const float4*>(bnb + d0);
    float4 b1v = *reinterpret_cast<const float4*>(bnb + d0 + 4);
    float bm[8] = {m0v.x, m0v.y, m0v.z, m0v.w, m1v.x, m1v.y, m1v.z, m1v.w};
    float bvv[8] = {v0v.x, v0v.y, v0v.z, v0v.w, v1v.x, v1v.y, v1v.z, v1v.w};
    float bg[8] = {g0v.x, g0v.y, g0v.z, g0v.w, g1v.x, g1v.y, g1v.z, g1v.w};
    float bb[8] = {b0v.x, b0v.y, b0v.z, b0v.w, b1v.x, b1v.y, b1v.z, b1v.w};
#pragma unroll
    for (int i = 0; i < 8; ++i) {
        float tt = acc[i] * invh + (float)rv[i];
        tt = (tt - bm[i]) * rsqrtf(bvv[i] + 1e-5f) * bg[i] + bb[i];
        o[i] = tt > 0.f ? tt : (__expf(tt) - 1.f);
    }

    // layer-2 projections
    float w2v[24], wrv[24];
    const f32x4* w2p = reinterpret_cast<const f32x4*>(W2 + (size_t)d0 * 3);
    const f32x4* wrp = reinterpret_cast<const f32x4*>(Wres2 + (size_t)d0 * 3);
#pragma unroll
    for (int j = 0; j < 6; ++j) {
        f32x4 a4 = w2p[j], c4 = wrp[j];
        w2v[4 * j] = a4[0]; w2v[4 * j + 1] = a4[1]; w2v[4 * j + 2] = a4[2]; w2v[4 * j + 3] = a4[3];
        wrv[4 * j] = c4[0]; wrv[4 * j + 1] = c4[1]; wrv[4 * j + 2] = c4[2]; wrv[4 * j + 3] = c4[3];
    }
    float pz[3] = {0.f, 0.f, 0.f}, pr[3] = {0.f, 0.f, 0.f};
#pragma unroll
    for (int idx = 0; idx < 24; ++idx) {
        pz[idx % 3] += o[idx / 3] * w2v[idx];
        pr[idx % 3] += o[idx / 3] * wrv[idx];
    }
#pragma unroll
    for (int off = 32; off > 0; off >>= 1) {
        pz[0] += __shfl_xor(pz[0], off); pz[1] += __shfl_xor(pz[1], off); pz[2] += __shfl_xor(pz[2], off);
        pr[0] += __shfl_xor(pr[0], off); pr[1] += __shfl_xor(pr[1], off); pr[2] += __shfl_xor(pr[2], off);
    }
    if (lane == 0) {
        float e2l = pz[0] * al2[0] + pz[1] * al2[1] + pz[2] * al2[2];
        float e2r = pz[0] * ar2[0] + pz[1] * ar2[1] + pz[2] * ar2[2];
        float4 v0 = make_float4(pz[0], pz[1], pz[2], e2l);
        float4 v1 = make_float4(pr[0], pr[1], pr[2], e2r);
        *reinterpret_cast<float4*>(node2 + (size_t)n * 8) = v0;
        *reinterpret_cast<float4*>(node2 + (size_t)n * 8 + 4) = v1;
    }
}

// ---------------- layer-2 aggregation: wave-per-node ----------------
__global__ __launch_bounds__(256) void agg2_k(const int* __restrict__ rowptr, const int* __restrict__ csr,
                                              const float* __restrict__ node2,
                                              const float* __restrict__ b2, float* __restrict__ out) {
    int wv = threadIdx.x >> 6, lane = threadIdx.x & 63;
    int n = blockIdx.x * 4 + wv;
    int beg = rowptr[n], deg = rowptr[n + 1] - beg;
    float ern = node2[(size_t)n * 8 + 7];
    float den = 0.f, a0 = 0.f, a1 = 0.f, a2 = 0.f;
    for (int j = lane; j < deg; j += 64) {
        int s = csr[beg + j];
        float4 v = *reinterpret_cast<const float4*>(node2 + (size_t)s * 8);
        float e = v.w + ern;
        e = e > 0.f ? e : SLOPE * e;
        float p = __expf(e);
        den += p;
        a0 += p * v.x; a1 += p * v.y; a2 += p * v.z;
    }
#pragma unroll
    for (int off = 32; off > 0; off >>= 1) {
        den += __shfl_xor(den, off);
        a0 += __shfl_xor(a0, off); a1 += __shfl_xor(a1, off); a2 += __shfl_xor(a2, off);
    }
    if (lane == 0) {
        float inv = deg > 0 ? 1.f / den : 0.f;
        float4 r = *reinterpret_cast<const float4*>(node2 + (size_t)n * 8 + 4);
        out[(size_t)n * 3 + 0] = a0 * inv + r.x + b2[0];
        out[(size_t)n * 3 + 1] = a1 * inv + r.y + b2[1];
        out[(size_t)n * 3 + 2] = a2 * inv + r.z + b2[2];
    }
}

extern "C" void kernel_launch(void* const* d_in, const int* in_sizes, int n_in,
                              void* d_out, int out_size, void* d_ws, size_t ws_size,
                              hipStream_t stream) {
    const float* X     = (const float*)d_in[0];
    const int*   src   = (const int*)d_in[1];
    const int*   dst   = (const int*)d_in[2];
    const float* W1    = (const float*)d_in[3];
    const float* al1   = (const float*)d_in[4];
    const float* ar1   = (const float*)d_in[5];
    const float* b1    = (const float*)d_in[6];
    const float* Wres1 = (const float*)d_in[7];
    const float* bng   = (const float*)d_in[8];
    const float* bnb   = (const float*)d_in[9];
    const float* bnm   = (const float*)d_in[10];
    const float* bnv   = (const float*)d_in[11];
    const float* W2    = (const float*)d_in[12];
    const float* al2   = (const float*)d_in[13];
    const float* ar2   = (const float*)d_in[14];
    const float* b2    = (const float*)d_in[15];
    const float* Wres2 = (const float*)d_in[16];
    float* out = (float*)d_out;

    char* p = (char*)d_ws;
    auto carve = [&](size_t bytes) -> char* {
        char* r = p;
        p += (bytes + 255) & ~(size_t)255;
        return r;
    };
    bf16*  BT     = (bf16*)carve((size_t)1024 * FIN * 2);   // [1024][128]: W1T rows 0-511, WresT rows 512-1023
    float* wl     = (float*)carve((size_t)FIN * 4 * 4);
    float* wr     = (float*)carve((size_t)FIN * 4 * 4);
    float* el     = (float*)carve((size_t)N_NODES * 4 * 4);
    float* er     = (float*)carve((size_t)N_NODES * 4 * 4);
    int*   deg    = (int*)carve((size_t)N_NODES * 4);
    int*   rowptr = (int*)carve((size_t)(N_NODES + 1) * 4);
    int*   cursor = (int*)carve((size_t)N_NODES * 4);
    int*   blksum = (int*)carve((size_t)256 * 4);
    int*   csr    = (int*)carve((size_t)N_EDGES * 4);
    bf16*  ZR     = (bf16*)carve((size_t)N_NODES * 1024 * 2);
    float* node2  = (float*)carve((size_t)N_NODES * 8 * 4);
    size_t need = (size_t)(p - (char*)d_ws);
    if (need > ws_size) {
        sentinel_k<<<(out_size + 255) / 256, 256, 0, stream>>>(out, out_size);
        return;
    }

    prep_k<<<196 + 512 + 2, 256, 0, stream>>>(W1, Wres1, al1, ar1, BT, wl, wr, deg);
    eler_k<<<N_NODES / 4, 256, 0, stream>>>(X, wl, wr, el, er);
    hist_k<<<(N_EDGES + 255) / 256, 256, 0, stream>>>(dst, deg);
    scan1_k<<<196, 256, 0, stream>>>(deg, rowptr, blksum);
    scan2_k<<<1, 256, 0, stream>>>(blksum);
    scan3_k<<<196, 256, 0, stream>>>(blksum, rowptr, cursor);
    fill_k<<<(N_EDGES + 255) / 256, 256, 0, stream>>>(src, dst, cursor, csr);
    gemm_k<<<dim3(8, (N_NODES + 63) / 64), 256, 0, stream>>>(X, BT, b1, ZR);
    agg1_k<<<N_NODES / 4, 256, 0, stream>>>(rowptr, csr, el, er, ZR,
                                            bng, bnb, bnm, bnv, W2, Wres2, al2, ar2, node2);
    agg2_k<<<N_NODES / 4, 256, 0, stream>>>(rowptr, csr, node2, b2, out);
}

// Round 9
// 201.478 us; speedup vs baseline: 1.8197x; 1.1340x over previous
//
#include <hip/hip_runtime.h>
#include <hip/hip_bf16.h>

#define N_NODES 50000
#define N_EDGES 400000
#define FIN     128
#define HD      512
#define SLOPE   0.2f

typedef __hip_bfloat16 bf16;
typedef __bf16 bf16x8 __attribute__((ext_vector_type(8)));
typedef __bf16 bf16x4 __attribute__((ext_vector_type(4)));
typedef __bf16 bf16x2 __attribute__((ext_vector_type(2)));
typedef float  f32x4  __attribute__((ext_vector_type(4)));

// ---------------- sentinel (workspace too small diagnostic) ----------------
__global__ void sentinel_k(float* out, int n) {
    int i = blockIdx.x * 256 + threadIdx.x;
    if (i < n) out[i] = 12288.0f;
}

// ---- prep: zero deg | Wcomb[gc][256k] = [W1;Wres1] col gc | Wp[gc][8] = {W2row,0,Wres2row,0} | wl/wr ----
__global__ __launch_bounds__(256) void prep_k(const float* __restrict__ W1, const float* __restrict__ Wres1,
                                              const float* __restrict__ al1, const float* __restrict__ ar1,
                                              const float* __restrict__ W2, const float* __restrict__ Wres2,
                                              bf16* __restrict__ Wcomb, float* __restrict__ Wp,
                                              float* __restrict__ wl, float* __restrict__ wr,
                                              int* __restrict__ deg) {
    int b = blockIdx.x;
    if (b < 196) {
        int i = b * 256 + threadIdx.x;
        if (i < N_NODES) deg[i] = 0;
        return;
    }
    b -= 196;
    if (b < 512) {                       // Wcomb row b (out-channel), thread = k
        int k = threadIdx.x;
        float v = (k < 128) ? W1[k * HD + b] : Wres1[(k - 128) * HD + b];
        Wcomb[b * 256 + k] = __float2bfloat16(v);
        return;
    }
    b -= 512;
    if (b < 16) {                        // Wp
        int i = b * 256 + threadIdx.x;   // 0..4095
        int row = i >> 3, c = i & 7;
        float v = 0.f;
        if (c < 3) v = W2[row * 3 + c];
        else if (c >= 4 && c < 7) v = Wres2[row * 3 + (c - 4)];
        Wp[i] = v;
        return;
    }
    b -= 16;                             // wl/wr: 2 blocks cover 128k x 4h
    int i = b * 256 + threadIdx.x;
    int k = i >> 2, h = i & 3;
    float sl = 0.f, sr = 0.f;
    for (int d = 0; d < 128; ++d) {
        float w = W1[k * HD + h * 128 + d];
        sl += w * al1[h * 128 + d];
        sr += w * ar1[h * 128 + d];
    }
    wl[k * 4 + h] = sl;
    wr[k * 4 + h] = sr;
}

// ---------------- el/er per node (wave-per-node) + Xb bf16 convert ----------------
__global__ __launch_bounds__(256) void eler_k(const float* __restrict__ X,
                                              const float* __restrict__ wl, const float* __restrict__ wr,
                                              float* __restrict__ el, float* __restrict__ er,
                                              bf16* __restrict__ Xb) {
    int w = threadIdx.x >> 6, lane = threadIdx.x & 63;
    int n = blockIdx.x * 4 + w;
    float x1 = X[(size_t)n * FIN + lane];
    float x2 = X[(size_t)n * FIN + 64 + lane];
    Xb[(size_t)n * FIN + lane] = __float2bfloat16(x1);
    Xb[(size_t)n * FIN + 64 + lane] = __float2bfloat16(x2);
    float pl[4], pr[4];
#pragma unroll
    for (int h = 0; h < 4; ++h) {
        pl[h] = x1 * wl[lane * 4 + h] + x2 * wl[(lane + 64) * 4 + h];
        pr[h] = x1 * wr[lane * 4 + h] + x2 * wr[(lane + 64) * 4 + h];
    }
#pragma unroll
    for (int off = 32; off > 0; off >>= 1) {
#pragma unroll
        for (int h = 0; h < 4; ++h) {
            pl[h] += __shfl_xor(pl[h], off);
            pr[h] += __shfl_xor(pr[h], off);
        }
    }
    if (lane == 0) {
        *reinterpret_cast<float4*>(el + (size_t)n * 4) = make_float4(pl[0], pl[1], pl[2], pl[3]);
        *reinterpret_cast<float4*>(er + (size_t)n * 4) = make_float4(pr[0], pr[1], pr[2], pr[3]);
    }
}

// ---------------- CSR build ----------------
__global__ void hist_k(const int* __restrict__ dst, int* __restrict__ deg) {
    int e = blockIdx.x * 256 + threadIdx.x;
    if (e < N_EDGES) atomicAdd(&deg[dst[e]], 1);
}

__global__ __launch_bounds__(256) void scan1_k(const int* __restrict__ deg,
                                               int* __restrict__ rowptr, int* __restrict__ blksum) {
    __shared__ int wsum[4];
    int t = threadIdx.x, b = blockIdx.x;
    int i = b * 256 + t;
    int v = (i < N_NODES) ? deg[i] : 0;
    int lane = t & 63, w = t >> 6;
    int x = v;
#pragma unroll
    for (int off = 1; off < 64; off <<= 1) {
        int y = __shfl_up(x, off);
        if (lane >= off) x += y;
    }
    if (lane == 63) wsum[w] = x;
    __syncthreads();
    int wadd = 0;
    if (w > 0) wadd += wsum[0];
    if (w > 1) wadd += wsum[1];
    if (w > 2) wadd += wsum[2];
    int incl = x + wadd;
    if (i < N_NODES) rowptr[i] = incl - v;
    if (t == 255) blksum[b] = incl;
}

__global__ __launch_bounds__(256) void scan2_k(int* __restrict__ blksum) {
    __shared__ int wsum[4];
    int t = threadIdx.x;
    int v = (t < 196) ? blksum[t] : 0;
    int lane = t & 63, w = t >> 6;
    int x = v;
#pragma unroll
    for (int off = 1; off < 64; off <<= 1) {
        int y = __shfl_up(x, off);
        if (lane >= off) x += y;
    }
    if (lane == 63) wsum[w] = x;
    __syncthreads();
    int wadd = 0;
    if (w > 0) wadd += wsum[0];
    if (w > 1) wadd += wsum[1];
    if (w > 2) wadd += wsum[2];
    if (t < 196) blksum[t] = x + wadd - v;
}

__global__ __launch_bounds__(256) void scan3_k(const int* __restrict__ blksum,
                                               int* __restrict__ rowptr, int* __restrict__ cursor) {
    int b = blockIdx.x;
    int i = b * 256 + threadIdx.x;
    if (i < N_NODES) {
        int v = rowptr[i] + blksum[b];
        rowptr[i] = v;
        cursor[i] = v;
    }
    if (i == 0) rowptr[N_NODES] = N_EDGES;
}

__global__ void fill_k(const int* __restrict__ src, const int* __restrict__ dst,
                       int* __restrict__ cursor, int* __restrict__ csr) {
    int e = blockIdx.x * 256 + threadIdx.x;
    if (e < N_EDGES) {
        int pos = atomicAdd(&cursor[dst[e]], 1);
        csr[pos] = src[e];
    }
}

// ---------------- X-space aggregation: AGG[n][h*128+c] = sum_e alpha^h_e Xb[src_e][c] ----------------
// wave-per-node; Xb working set 12.8 MB -> L2-resident gathers; 4B/lane/edge.
__global__ __launch_bounds__(256) void aggX_k(const int* __restrict__ rowptr, const int* __restrict__ csr,
                                              const float* __restrict__ el, const float* __restrict__ er,
                                              const bf16* __restrict__ Xb, bf16* __restrict__ AGGb) {
    __shared__ int    ssrc[4][64];
    __shared__ float4 spe4[4][64];

    const int w = threadIdx.x >> 6, lane = threadIdx.x & 63;
    const int n = blockIdx.x * 4 + w;
    const int beg = rowptr[n];
    const int deg = rowptr[n + 1] - beg;
    const float4 ern = *reinterpret_cast<const float4*>(er + (size_t)n * 4);

    float acc[4][2] = {{0.f,0.f},{0.f,0.f},{0.f,0.f},{0.f,0.f}};
    float4 den = make_float4(0.f, 0.f, 0.f, 0.f);

    for (int base = 0; base < deg; base += 64) {
        const int cnt = min(64, deg - base);
        if (lane < cnt) {
            int s = csr[beg + base + lane];
            ssrc[w][lane] = s;
            float4 e4 = *reinterpret_cast<const float4*>(el + (size_t)s * 4);
            float4 p; float e;
            e = e4.x + ern.x; e = e > 0.f ? e : SLOPE * e; p.x = __expf(e);
            e = e4.y + ern.y; e = e > 0.f ? e : SLOPE * e; p.y = __expf(e);
            e = e4.z + ern.z; e = e > 0.f ? e : SLOPE * e; p.z = __expf(e);
            e = e4.w + ern.w; e = e > 0.f ? e : SLOPE * e; p.w = __expf(e);
            den.x += p.x; den.y += p.y; den.z += p.z; den.w += p.w;
            spe4[w][lane] = p;
        }
        asm volatile("s_waitcnt lgkmcnt(0)" ::: "memory");
        for (int jj = 0; jj < cnt; jj += 4) {
            unsigned xv[4]; float4 pk[4];
#pragma unroll
            for (int k2 = 0; k2 < 4; ++k2) {
                int j2 = jj + k2;
                int jc = j2 < cnt ? j2 : cnt - 1;
                int s = ssrc[w][jc];
                xv[k2] = *reinterpret_cast<const unsigned*>(
                    reinterpret_cast<const char*>(Xb) + (size_t)s * 256 + lane * 4);
                float4 p = spe4[w][jc];
                if (j2 >= cnt) p = make_float4(0.f, 0.f, 0.f, 0.f);
                pk[k2] = p;
            }
#pragma unroll
            for (int k2 = 0; k2 < 4; ++k2) {
                float xlo = __uint_as_float(xv[k2] << 16);
                float xhi = __uint_as_float(xv[k2] & 0xffff0000u);
                acc[0][0] += pk[k2].x * xlo; acc[0][1] += pk[k2].x * xhi;
                acc[1][0] += pk[k2].y * xlo; acc[1][1] += pk[k2].y * xhi;
                acc[2][0] += pk[k2].z * xlo; acc[2][1] += pk[k2].z * xhi;
                acc[3][0] += pk[k2].w * xlo; acc[3][1] += pk[k2].w * xhi;
            }
        }
        asm volatile("s_waitcnt lgkmcnt(0)" ::: "memory");   // WAR guard before next chunk
    }

#pragma unroll
    for (int off = 32; off > 0; off >>= 1) {
        den.x += __shfl_xor(den.x, off);
        den.y += __shfl_xor(den.y, off);
        den.z += __shfl_xor(den.z, off);
        den.w += __shfl_xor(den.w, off);
    }
    float inv[4] = {0.f, 0.f, 0.f, 0.f};
    if (deg > 0) {
        inv[0] = 1.f / den.x; inv[1] = 1.f / den.y;
        inv[2] = 1.f / den.z; inv[3] = 1.f / den.w;
    }
#pragma unroll
    for (int h = 0; h < 4; ++h) {
        bf16x2 v = {(__bf16)(acc[h][0] * inv[h]), (__bf16)(acc[h][1] * inv[h])};
        *reinterpret_cast<bf16x2*>(AGGb + (size_t)n * 512 + h * 128 + lane * 2) = v;
    }
}

// ---------------- fused GEMM2: h = [AGG_h | Xb]·[W1_h;Wres1_h] + b1 -> BN -> ELU -> W2/Wres2 proj ----------------
// block = 64 nodes; h-loop over 4 head-quadrants; per wave 32 out-ch; K=256 MFMA from swizzled LDS.
// D-mapping (verified R7 gemm v4): a = W-frag (row gc0+cl), b = node-frag (row mt*16+cl);
// acc[i] = [ch gc0+rg*4+i][node mt*16+cl].
__global__ __launch_bounds__(256) void gemm2_k(
    const bf16* __restrict__ Xb, const bf16* __restrict__ AGGb,
    const bf16* __restrict__ Wcomb, const float* __restrict__ bias1,
    const float* __restrict__ bnm, const float* __restrict__ bnv,
    const float* __restrict__ bng, const float* __restrict__ bnb,
    const float* __restrict__ Wp, const float* __restrict__ al2, const float* __restrict__ ar2,
    float* __restrict__ node2) {
    __shared__ __align__(16) char AS[64 * 512];    // rows: [0..255]=AGG_h k0..127, [256..511]=Xb k128..255
    __shared__ float zsum[4][64][6];

    const int t = threadIdx.x;
    const int w = t >> 6, lane = t & 63;
    const int cl = lane & 15, rg = lane >> 4;
    const int m0 = blockIdx.x * 64;

    // stage Xb half once
#pragma unroll
    for (int j = 0; j < 4; ++j) {
        int L = j * 4096 + t * 16;
        int row = L >> 8, col = L & 255;
        int grow = m0 + row; grow = grow < N_NODES ? grow : N_NODES - 1;
        bf16x8 v = *reinterpret_cast<const bf16x8*>(
            reinterpret_cast<const char*>(Xb) + (size_t)grow * 256 + col);
        int byte = (row * 512 + 256 + col) ^ ((row & 7) << 4);
        *reinterpret_cast<bf16x8*>(AS + byte) = v;
    }

    float z2p[4][3] = {}, r2p[4][3] = {};

    for (int h = 0; h < 4; ++h) {
        __syncthreads();   // protects Xb stage (h=0) and WAR on AGG restage (h>0)
#pragma unroll
        for (int j = 0; j < 4; ++j) {
            int L = j * 4096 + t * 16;
            int row = L >> 8, col = L & 255;
            int grow = m0 + row; grow = grow < N_NODES ? grow : N_NODES - 1;
            bf16x8 v = *reinterpret_cast<const bf16x8*>(
                reinterpret_cast<const char*>(AGGb) + (size_t)grow * 1024 + h * 256 + col);
            int byte = (row * 512 + col) ^ ((row & 7) << 4);
            *reinterpret_cast<bf16x8*>(AS + byte) = v;
        }
        __syncthreads();

#pragma unroll
        for (int ct = 0; ct < 2; ++ct) {
            const int gc0 = h * 128 + w * 32 + ct * 16;
            bf16x8 af[8];
#pragma unroll
            for (int ks = 0; ks < 8; ++ks)
                af[ks] = *reinterpret_cast<const bf16x8*>(
                    reinterpret_cast<const char*>(Wcomb) + (size_t)(gc0 + cl) * 512 + ks * 64 + rg * 16);
            const int gcl = gc0 + rg * 4;
            f32x4 biasv = *reinterpret_cast<const f32x4*>(bias1 + gcl);
            f32x4 bnm4 = *reinterpret_cast<const f32x4*>(bnm + gcl);
            f32x4 bnv4 = *reinterpret_cast<const f32x4*>(bnv + gcl);
            f32x4 bng4 = *reinterpret_cast<const f32x4*>(bng + gcl);
            f32x4 bnb4 = *reinterpret_cast<const f32x4*>(bnb + gcl);
            f32x4 rs;
#pragma unroll
            for (int i = 0; i < 4; ++i) rs[i] = rsqrtf(bnv4[i] + 1e-5f) * bng4[i];
            f32x4 wpa[4], wpb[4];
#pragma unroll
            for (int i = 0; i < 4; ++i) {
                wpa[i] = *reinterpret_cast<const f32x4*>(Wp + (size_t)(gcl + i) * 8);
                wpb[i] = *reinterpret_cast<const f32x4*>(Wp + (size_t)(gcl + i) * 8 + 4);
            }
#pragma unroll
            for (int mt = 0; mt < 4; ++mt) {
                int row = mt * 16 + cl;
                bf16x8 bfr[8];
#pragma unroll
                for (int ks = 0; ks < 8; ++ks) {
                    int byte = (row * 512 + ks * 64 + rg * 16) ^ ((row & 7) << 4);
                    bfr[ks] = *reinterpret_cast<const bf16x8*>(AS + byte);
                }
                f32x4 a = biasv;
#pragma unroll
                for (int ks = 0; ks < 8; ++ks)
                    a = __builtin_amdgcn_mfma_f32_16x16x32_bf16(af[ks], bfr[ks], a, 0, 0, 0);
#pragma unroll
                for (int i = 0; i < 4; ++i) {
                    float hv = (a[i] - bnm4[i]) * rs[i] + bnb4[i];
                    hv = hv > 0.f ? hv : (__expf(hv) - 1.f);
                    z2p[mt][0] += hv * wpa[i][0]; z2p[mt][1] += hv * wpa[i][1]; z2p[mt][2] += hv * wpa[i][2];
                    r2p[mt][0] += hv * wpb[i][0]; r2p[mt][1] += hv * wpb[i][1]; r2p[mt][2] += hv * wpb[i][2];
                }
            }
        }
    }

    // reduce across rg (4 lanes share node cl per mt)
#pragma unroll
    for (int mt = 0; mt < 4; ++mt)
#pragma unroll
        for (int c = 0; c < 3; ++c) {
            z2p[mt][c] += __shfl_xor(z2p[mt][c], 16);
            z2p[mt][c] += __shfl_xor(z2p[mt][c], 32);
            r2p[mt][c] += __shfl_xor(r2p[mt][c], 16);
            r2p[mt][c] += __shfl_xor(r2p[mt][c], 32);
        }
    if (rg == 0) {
#pragma unroll
        for (int mt = 0; mt < 4; ++mt) {
            int nl = mt * 16 + cl;
            zsum[w][nl][0] = z2p[mt][0]; zsum[w][nl][1] = z2p[mt][1]; zsum[w][nl][2] = z2p[mt][2];
            zsum[w][nl][3] = r2p[mt][0]; zsum[w][nl][4] = r2p[mt][1]; zsum[w][nl][5] = r2p[mt][2];
        }
    }
    __syncthreads();
    if (t < 64) {
        float v[6];
#pragma unroll
        for (int c = 0; c < 6; ++c)
            v[c] = zsum[0][t][c] + zsum[1][t][c] + zsum[2][t][c] + zsum[3][t][c];
        int n = m0 + t;
        if (n < N_NODES) {
            float e2l = v[0] * al2[0] + v[1] * al2[1] + v[2] * al2[2];
            float e2r = v[0] * ar2[0] + v[1] * ar2[1] + v[2] * ar2[2];
            *reinterpret_cast<float4*>(node2 + (size_t)n * 8) = make_float4(v[0], v[1], v[2], e2l);
            *reinterpret_cast<float4*>(node2 + (size_t)n * 8 + 4) = make_float4(v[3], v[4], v[5], e2r);
        }
    }
}

// ---------------- layer-2 aggregation: wave-per-node ----------------
__global__ __launch_bounds__(256) void agg2_k(const int* __restrict__ rowptr, const int* __restrict__ csr,
                                              const float* __restrict__ node2,
                                              const float* __restrict__ b2, float* __restrict__ out) {
    int wv = threadIdx.x >> 6, lane = threadIdx.x & 63;
    int n = blockIdx.x * 4 + wv;
    int beg = rowptr[n], deg = rowptr[n + 1] - beg;
    float ern = node2[(size_t)n * 8 + 7];
    float den = 0.f, a0 = 0.f, a1 = 0.f, a2 = 0.f;
    for (int j = lane; j < deg; j += 64) {
        int s = csr[beg + j];
        float4 v = *reinterpret_cast<const float4*>(node2 + (size_t)s * 8);
        float e = v.w + ern;
        e = e > 0.f ? e : SLOPE * e;
        float p = __expf(e);
        den += p;
        a0 += p * v.x; a1 += p * v.y; a2 += p * v.z;
    }
#pragma unroll
    for (int off = 32; off > 0; off >>= 1) {
        den += __shfl_xor(den, off);
        a0 += __shfl_xor(a0, off); a1 += __shfl_xor(a1, off); a2 += __shfl_xor(a2, off);
    }
    if (lane == 0) {
        float inv = deg > 0 ? 1.f / den : 0.f;
        float4 r = *reinterpret_cast<const float4*>(node2 + (size_t)n * 8 + 4);
        out[(size_t)n * 3 + 0] = a0 * inv + r.x + b2[0];
        out[(size_t)n * 3 + 1] = a1 * inv + r.y + b2[1];
        out[(size_t)n * 3 + 2] = a2 * inv + r.z + b2[2];
    }
}

extern "C" void kernel_launch(void* const* d_in, const int* in_sizes, int n_in,
                              void* d_out, int out_size, void* d_ws, size_t ws_size,
                              hipStream_t stream) {
    const float* X     = (const float*)d_in[0];
    const int*   src   = (const int*)d_in[1];
    const int*   dst   = (const int*)d_in[2];
    const float* W1    = (const float*)d_in[3];
    const float* al1   = (const float*)d_in[4];
    const float* ar1   = (const float*)d_in[5];
    const float* b1    = (const float*)d_in[6];
    const float* Wres1 = (const float*)d_in[7];
    const float* bng   = (const float*)d_in[8];
    const float* bnb   = (const float*)d_in[9];
    const float* bnm   = (const float*)d_in[10];
    const float* bnv   = (const float*)d_in[11];
    const float* W2    = (const float*)d_in[12];
    const float* al2   = (const float*)d_in[13];
    const float* ar2   = (const float*)d_in[14];
    const float* b2    = (const float*)d_in[15];
    const float* Wres2 = (const float*)d_in[16];
    float* out = (float*)d_out;

    char* p = (char*)d_ws;
    auto carve = [&](size_t bytes) -> char* {
        char* r = p;
        p += (bytes + 255) & ~(size_t)255;
        return r;
    };
    bf16*  Wcomb  = (bf16*)carve((size_t)512 * 256 * 2);
    float* Wp     = (float*)carve((size_t)512 * 8 * 4);
    float* wl     = (float*)carve((size_t)FIN * 4 * 4);
    float* wr     = (float*)carve((size_t)FIN * 4 * 4);
    float* el     = (float*)carve((size_t)N_NODES * 4 * 4);
    float* er     = (float*)carve((size_t)N_NODES * 4 * 4);
    int*   deg    = (int*)carve((size_t)N_NODES * 4);
    int*   rowptr = (int*)carve((size_t)(N_NODES + 1) * 4);
    int*   cursor = (int*)carve((size_t)N_NODES * 4);
    int*   blksum = (int*)carve((size_t)256 * 4);
    int*   csr    = (int*)carve((size_t)N_EDGES * 4);
    bf16*  Xb     = (bf16*)carve((size_t)N_NODES * FIN * 2);
    bf16*  AGGb   = (bf16*)carve((size_t)N_NODES * 512 * 2);
    float* node2  = (float*)carve((size_t)N_NODES * 8 * 4);
    size_t need = (size_t)(p - (char*)d_ws);
    if (need > ws_size) {
        sentinel_k<<<(out_size + 255) / 256, 256, 0, stream>>>(out, out_size);
        return;
    }

    prep_k<<<196 + 512 + 16 + 2, 256, 0, stream>>>(W1, Wres1, al1, ar1, W2, Wres2,
                                                   Wcomb, Wp, wl, wr, deg);
    eler_k<<<N_NODES / 4, 256, 0, stream>>>(X, wl, wr, el, er, Xb);
    hist_k<<<(N_EDGES + 255) / 256, 256, 0, stream>>>(dst, deg);
    scan1_k<<<196, 256, 0, stream>>>(deg, rowptr, blksum);
    scan2_k<<<1, 256, 0, stream>>>(blksum);
    scan3_k<<<196, 256, 0, stream>>>(blksum, rowptr, cursor);
    fill_k<<<(N_EDGES + 255) / 256, 256, 0, stream>>>(src, dst, cursor, csr);
    aggX_k<<<N_NODES / 4, 256, 0, stream>>>(rowptr, csr, el, er, Xb, AGGb);
    gemm2_k<<<(N_NODES + 63) / 64, 256, 0, stream>>>(Xb, AGGb, Wcomb, b1,
                                                     bnm, bnv, bng, bnb, Wp, al2, ar2, node2);
    agg2_k<<<N_NODES / 4, 256, 0, stream>>>(rowptr, csr, node2, b2, out);
}